// Round 9
// baseline (212.110 us; speedup 1.0000x reference)
//
#include <hip/hip_runtime.h>
#include <math.h>

#define N_NODES 100000
#define N_EDGES 1600000
#define D 64
#define RPB 128                  // rows per bucket
#define NBUK 782                 // ceil(N_NODES/128)
#define CAP 3072                 // LDS edge buffer (bucket mean 2048, +22 sigma)
#define NGB 782                  // gemm blocks (128 rows each)
#define NHB 784                  // sort blocks (FIRST in grid: poles start at t=0)
#define EPB 2048                 // edges per sort block (784*2048 >= 1.6M)
#define POFF_ROW 784             // u32 stride of poff[hb][*] (hb-major)

typedef unsigned int u32;
typedef unsigned short u16;

static __device__ __forceinline__ u32 f2bf(float x) {   // RNE fp32->bf16 (low 16)
    u32 u = __float_as_uint(x);
    u32 r = u + 0x7FFFu + ((u >> 16) & 1u);
    return r >> 16;
}
static __device__ __forceinline__ u32 pack2(float a, float b) {
    return f2bf(a) | (f2bf(b) << 16);
}
static __device__ __forceinline__ float bflo(u32 u) { return __uint_as_float(u << 16); }
static __device__ __forceinline__ float bfhi(u32 u) { return __uint_as_float(u & 0xFFFF0000u); }
static __device__ __forceinline__ float selu(float x) {
    const float scale = 1.0507009873554805f;
    const float alpha = 1.6732632423543772f;
    return x > 0.f ? scale * x : scale * alpha * (expf(x) - 1.f);
}
// 64-lane inclusive scan in-register (no barriers)
static __device__ __forceinline__ u32 wave_iscan(u32 x, int lane) {
    #pragma unroll
    for (int d = 1; d < 64; d <<= 1) {
        u32 y = __shfl_up(x, d, 64);
        if (lane >= d) x += y;
    }
    return x;
}

// ---------------------------------------------------------------------------
// K1 fused (unchanged from round 8). Blocks [0,784): in-LDS counting sort of
// 2048 edges by 128-row bucket into an LDS tile, flushed with coalesced
// streaks. Blocks [784,1566): bf16 h = feat @ kern (register-tiled 4r x 8c).
// ---------------------------------------------------------------------------
__global__ __launch_bounds__(256) void fused_gemm_sort(
    const float* __restrict__ feat, const float* __restrict__ kern,
    const int* __restrict__ erow, const int* __restrict__ ecol,
    const float* __restrict__ eval, u16* __restrict__ hbf,
    int2* __restrict__ sedge, u32* __restrict__ poff)
{
    __shared__ u32 smem[5665];   // 22.7 KB: gemm uses 16 KB; sort uses all
    const int t = threadIdx.x;

    if (blockIdx.x >= NHB) {
        float* ks = (float*)smem;   // 64x64 kernel, row-major [k][c]
        {
            const float4* k4 = (const float4*)kern;
            float4* ks4 = (float4*)ks;
            #pragma unroll
            for (int i = 0; i < 4; i++) ks4[t + 256 * i] = k4[t + 256 * i];
        }
        __syncthreads();

        const int cgi  = t & 7;                      // 8 col-groups (8 cols)
        const int rg   = t >> 3;                     // 32 row-groups (4 rows)
        const int row0 = (blockIdx.x - NHB) * RPB + rg * 4;

        float4 acc[4][2];
        #pragma unroll
        for (int r = 0; r < 4; r++)
            #pragma unroll
            for (int i = 0; i < 2; i++)
                acc[r][i] = make_float4(0.f, 0.f, 0.f, 0.f);

        #pragma unroll 4
        for (int s = 0; s < 16; s++) {               // k4-step: 4 k-values
            float4 f[4];
            #pragma unroll
            for (int r = 0; r < 4; r++) {
                int row = min(row0 + r, N_NODES - 1);
                f[r] = ((const float4*)(feat + (size_t)row * D))[s];
            }
            float4 kk[4][2];
            #pragma unroll
            for (int kv = 0; kv < 4; kv++)
                #pragma unroll
                for (int i = 0; i < 2; i++)
                    kk[kv][i] = ((const float4*)(ks + (s * 4 + kv) * D))[cgi * 2 + i];
            #pragma unroll
            for (int r = 0; r < 4; r++) {
                #pragma unroll
                for (int kv = 0; kv < 4; kv++) {
                    float fv = (&f[r].x)[kv];
                    #pragma unroll
                    for (int i = 0; i < 2; i++) {
                        acc[r][i].x += fv * kk[kv][i].x;
                        acc[r][i].y += fv * kk[kv][i].y;
                        acc[r][i].z += fv * kk[kv][i].z;
                        acc[r][i].w += fv * kk[kv][i].w;
                    }
                }
            }
        }

        #pragma unroll
        for (int r = 0; r < 4; r++) {
            int row = row0 + r;
            if (row < N_NODES) {
                uint4 o;
                o.x = pack2(acc[r][0].x, acc[r][0].y);
                o.y = pack2(acc[r][0].z, acc[r][0].w);
                o.z = pack2(acc[r][1].x, acc[r][1].y);
                o.w = pack2(acc[r][1].z, acc[r][1].w);
                ((uint4*)(hbf + (size_t)row * D))[cgi] = o;
            }
        }
    } else {
        int2* tile = (int2*)smem;          // 2048 int2 = 16 KB sorted tile
        u32* co    = smem + 4096;          // 783: counts, then offsets in-place
        u32* cu    = co + 783;             // 782 cursors
        u32* part  = cu + 782;             // 4 wave partials   (total 5665 u32)

        for (int i = t; i < 783; i += 256) co[i] = 0u;
        __syncthreads();

        const int hb   = blockIdx.x;
        const int base = hb * EPB;
        const int lane = t & 63;
        const int w    = t >> 6;

        // pass 1: bucket count (native u32 LDS atomics), coalesced erow reads
        #pragma unroll
        for (int k = 0; k < 8; k++) {
            int i = base + k * 256 + t;
            if (i < N_EDGES) atomicAdd(&co[(u32)erow[i] >> 7], 1u);
        }
        __syncthreads();

        // shfl-based exclusive scan over 782 counts, offsets written in-place
        const int i0 = t * 4;
        u32 p = 0u;
        #pragma unroll
        for (int jj = 0; jj < 4; jj++) { int i = i0 + jj; if (i < NBUK) p += co[i]; }
        u32 incl = wave_iscan(p, lane);
        if (lane == 63) part[w] = incl;
        __syncthreads();
        {
            u32 wp = 0u;
            #pragma unroll
            for (int ww = 0; ww < 4; ww++) if (ww < w) wp += part[ww];
            u32 run = incl - p + wp;
            #pragma unroll
            for (int jj = 0; jj < 4; jj++) {
                int i = i0 + jj;
                if (i < NBUK) { u32 cv = co[i]; co[i] = run; cu[i] = run; run += cv; }
            }
            if (t == 0) co[NBUK] = part[0] + part[1] + part[2] + part[3];
        }
        __syncthreads();

        // pass 2: re-read erow (L2-hot), scatter into LDS tile
        #pragma unroll
        for (int k = 0; k < 8; k++) {
            int i = base + k * 256 + t;
            if (i < N_EDGES) {
                u32 r = (u32)erow[i];
                u32 rk = atomicAdd(&cu[r >> 7], 1u);
                tile[rk] = make_int2(ecol[i] | (int)((r & 127u) << 17),
                                     __float_as_int(eval[i]));
            }
        }
        __syncthreads();

        // flush: fully coalesced contiguous int2 stores (slots >= cnt are
        // garbage but never read -- poff runs only cover [0, cnt))
        #pragma unroll
        for (int k = 0; k < 8; k++)
            sedge[(size_t)hb * EPB + k * 256 + t] = tile[k * 256 + t];

        // publish 783 offsets, hb-major: fully coalesced contiguous writes
        for (int i = t; i <= NBUK; i += 256)
            poff[(size_t)hb * POFF_ROW + i] = co[i];
    }
}

// ---------------------------------------------------------------------------
// K2: aggregation. Staging (O(1) runid lookup) unchanged.
// Phase C changes vs round 8:
//  - degree-perm REVERTED (it scattered the epilogue: WRITE_SIZE 25->31 MB,
//    FETCH +5 MB -- net negative; g maps to row directly again).
//  - straight-line 8-WIDE gather batch: 8 independent uint4 loads in flight
//    before any consuming FMA. Round 8's copy-rotated dbuf was collapsed by
//    the compiler (VGPR stayed 32); a flat wide batch cannot be collapsed --
//    VGPR ~52-64 is the expected signature. Halves batch-drain count at
//    avg degree 16 (4 drains -> 2).
// ---------------------------------------------------------------------------
__global__ __launch_bounds__(1024, 8) void agg_kernel(
    const u32* __restrict__ poff, const int2* __restrict__ sedge,
    const u16* __restrict__ hbf, const float* __restrict__ skip,
    const float* __restrict__ bias, float* __restrict__ out)
{
    __shared__ int2 eA[CAP];          // 24 KB staged (bucket-contiguous)
    __shared__ int2 eB[CAP];          // 24 KB row-sorted
    __shared__ u32 c[RPB];
    __shared__ u32 o[RPB];
    __shared__ u32 cur[RPB];
    __shared__ u32 combo[NHB];        // rs0[rid] - excl[rid]  (mod 2^32)
    __shared__ u16 runid[CAP];        // edge index -> run id
    __shared__ u32 wsum[16];
    __shared__ u32 wpre[16];
    __shared__ u32 cnt_sh;

    const int t = threadIdx.x;
    const int lane = t & 63;
    const int w = t >> 6;
    const int b = blockIdx.x;

    if (t < RPB) c[t] = 0u;

    // run descriptors: hb-major poff -> scattered 4B loads, L2-hot (97x reuse)
    u32 mylen = 0u, s0 = 0u;
    if (t < NHB) {
        const u32* pr = poff + (size_t)t * POFF_ROW + b;
        s0    = pr[0];
        mylen = pr[1] - s0;
    }
    // shfl scan of 784 run lengths: wave scans + 16 wave partials
    u32 incl = wave_iscan(mylen, lane);
    if (lane == 63) wsum[w] = incl;
    __syncthreads();
    if (w == 0) {
        u32 v = (lane < 16) ? wsum[lane] : 0u;
        u32 pp = wave_iscan(v, lane);
        if (lane < 16) wpre[lane] = pp - v;       // exclusive wave prefix
        if (lane == 15) cnt_sh = min(pp, (u32)CAP);
    }
    __syncthreads();
    incl += wpre[w];
    const u32 excl = incl - mylen;
    if (t < NHB) {
        combo[t] = s0 - excl;                      // wrapping arithmetic
        for (u32 j = excl; j < incl; j++)
            if (j < (u32)CAP) runid[j] = (u16)t;
    }
    __syncthreads();

    const u32 cnt = cnt_sh;

    // stage: edge-parallel, O(1) run lookup, single global read, row count
    for (u32 j = (u32)t; j < cnt; j += 1024u) {
        u32 rid = (u32)runid[j];
        u32 src = rid * (u32)EPB + combo[rid] + j; // == rid*EPB + rs0 + (j-excl)
        int2 e = sedge[(size_t)src];
        eA[j] = e;
        atomicAdd(&c[(u32)e.x >> 17], 1u);
    }
    __syncthreads();

    // shfl-based exclusive scan over 128 row counts (2 barriers)
    {
        u32 x = (t < RPB) ? c[t] : 0u;
        u32 ri = wave_iscan(x, lane);
        if (lane == 63) wsum[w] = ri;
        __syncthreads();
        if (t < RPB) {
            u32 add = (w == 1) ? wsum[0] : 0u;
            u32 e = ri + add - x;
            o[t] = e; cur[t] = e;
        }
        __syncthreads();
    }

    // scatter LDS->LDS into row-sorted eB (rk < cnt <= CAP by construction)
    for (u32 j = (u32)t; j < cnt; j += 1024u) {
        int2 e = eA[j];
        u32 rl = (u32)e.x >> 17;
        u32 rk = atomicAdd(&cur[rl], 1u);
        eB[rk] = make_int2(e.x & 0x1FFFF, e.y);
    }
    __syncthreads();

    // phase C: one row per 8-lane group, 8 dims/lane, 8-wide flat batches
    const int rows = min(RPB, N_NODES - b * RPB);
    const int g  = t >> 3;            // 0..127: local row
    const int dg = t & 7;             // dim group (8 dims = one uint4)

    float a0 = 0.f, a1 = 0.f, a2 = 0.f, a3 = 0.f;
    float a4 = 0.f, a5 = 0.f, a6 = 0.f, a7 = 0.f;

    u32 jb = 0u, jend = 0u;
    if (g < rows) {
        jb = o[g];
        jend = min(jb + c[g], (u32)CAP);
    }

#define GLD(J, E, V, H) do {                                          \
        int2 E = eB[(J)];                                             \
        V = __int_as_float(E.y);                                      \
        H = ((const uint4*)(hbf + (size_t)E.x * D))[dg];              \
    } while (0)
#define FMA1(H, V) do {                                               \
        a0 += (V) * bflo((H).x); a1 += (V) * bfhi((H).x);             \
        a2 += (V) * bflo((H).y); a3 += (V) * bfhi((H).y);             \
        a4 += (V) * bflo((H).z); a5 += (V) * bfhi((H).z);             \
        a6 += (V) * bflo((H).w); a7 += (V) * bfhi((H).w);             \
    } while (0)

    u32 j = jb;
    for (; j + 7u < jend; j += 8u) {      // 8 independent gathers in flight
        uint4 h0, h1, h2, h3, h4, h5, h6, h7;
        float v0, v1, v2, v3, v4, v5, v6, v7;
        GLD(j,      e0, v0, h0); GLD(j + 1u, e1, v1, h1);
        GLD(j + 2u, e2, v2, h2); GLD(j + 3u, e3, v3, h3);
        GLD(j + 4u, e4, v4, h4); GLD(j + 5u, e5, v5, h5);
        GLD(j + 6u, e6, v6, h6); GLD(j + 7u, e7, v7, h7);
        FMA1(h0, v0); FMA1(h1, v1); FMA1(h2, v2); FMA1(h3, v3);
        FMA1(h4, v4); FMA1(h5, v5); FMA1(h6, v6); FMA1(h7, v7);
    }
    for (; j + 3u < jend; j += 4u) {
        uint4 h0, h1, h2, h3;
        float v0, v1, v2, v3;
        GLD(j,      e0, v0, h0); GLD(j + 1u, e1, v1, h1);
        GLD(j + 2u, e2, v2, h2); GLD(j + 3u, e3, v3, h3);
        FMA1(h0, v0); FMA1(h1, v1); FMA1(h2, v2); FMA1(h3, v3);
    }
    for (; j < jend; j++) {
        uint4 h0; float v0;
        GLD(j, e0, v0, h0);
        FMA1(h0, v0);
    }
#undef GLD
#undef FMA1

    // epilogue: all lanes active (8 lanes x 8 dims per row), coalesced
    if (g < rows) {
        const int grow = b * RPB + g;
        uint4 hr = ((const uint4*)(hbf + (size_t)grow * D))[dg];
        float4 s0v = ((const float4*)skip)[2 * dg];
        float4 s1v = ((const float4*)skip)[2 * dg + 1];
        float4 b0v = ((const float4*)bias)[2 * dg];
        float4 b1v = ((const float4*)bias)[2 * dg + 1];
        float4 x0, x1;
        x0.x = selu(bflo(hr.x) * s0v.x + b0v.x + a0);
        x0.y = selu(bfhi(hr.x) * s0v.y + b0v.y + a1);
        x0.z = selu(bflo(hr.y) * s0v.z + b0v.z + a2);
        x0.w = selu(bfhi(hr.y) * s0v.w + b0v.w + a3);
        x1.x = selu(bflo(hr.z) * s1v.x + b1v.x + a4);
        x1.y = selu(bfhi(hr.z) * s1v.y + b1v.y + a5);
        x1.z = selu(bflo(hr.w) * s1v.z + b1v.z + a6);
        x1.w = selu(bfhi(hr.w) * s1v.w + b1v.w + a7);
        ((float4*)(out + (size_t)grow * D))[2 * dg]     = x0;
        ((float4*)(out + (size_t)grow * D))[2 * dg + 1] = x1;
    }
}

extern "C" void kernel_launch(void* const* d_in, const int* in_sizes, int n_in,
                              void* d_out, int out_size, void* d_ws, size_t ws_size,
                              hipStream_t stream)
{
    const float* feat = (const float*)d_in[0];
    const float* kern = (const float*)d_in[1];
    const float* bias = (const float*)d_in[2];
    const float* skip = (const float*)d_in[3];
    const int*   erow = (const int*)d_in[4];
    const int*   ecol = (const int*)d_in[5];
    const float* eval = (const float*)d_in[6];
    float* out = (float*)d_out;

    // workspace layout (all segments 16B-aligned)
    u16*  hbf   = (u16*)d_ws;                             // 6,400,000 u16 (12.8 MB)
    u32*  poff  = (u32*)(hbf + (size_t)N_NODES * D);      // 784*784 u32 (2.46 MB)
    int2* sedge = (int2*)(poff + (size_t)NHB * POFF_ROW); // 784*2048 int2 (12.85 MB)
    // total ~28.1 MB

    hipLaunchKernelGGL(fused_gemm_sort, dim3(NGB + NHB), dim3(256), 0, stream,
                       feat, kern, erow, ecol, eval, hbf, sedge, poff);
    hipLaunchKernelGGL(agg_kernel, dim3(NBUK), dim3(1024), 0, stream,
                       poff, sedge, hbf, skip, bias, out);
}

// Round 10
// 170.150 us; speedup vs baseline: 1.2466x; 1.2466x over previous
//
#include <hip/hip_runtime.h>
#include <math.h>

#define N_NODES 100000
#define N_EDGES 1600000
#define D 64
#define RPB 128                  // rows per bucket
#define NBUK 782                 // ceil(N_NODES/128)
#define CAP 3072                 // LDS edge buffer (bucket mean 2048, +22 sigma)
#define NGB 782                  // gemm blocks (128 rows each)
#define NHB 784                  // sort blocks (FIRST in grid: poles start at t=0)
#define EPB 2048                 // edges per sort block (784*2048 >= 1.6M)
#define POFF_ROW 784             // u32 stride of poff[hb][*] (hb-major)

typedef unsigned int u32;
typedef unsigned short u16;

static __device__ __forceinline__ u32 f2bf(float x) {   // RNE fp32->bf16 (low 16)
    u32 u = __float_as_uint(x);
    u32 r = u + 0x7FFFu + ((u >> 16) & 1u);
    return r >> 16;
}
static __device__ __forceinline__ u32 pack2(float a, float b) {
    return f2bf(a) | (f2bf(b) << 16);
}
static __device__ __forceinline__ float bflo(u32 u) { return __uint_as_float(u << 16); }
static __device__ __forceinline__ float bfhi(u32 u) { return __uint_as_float(u & 0xFFFF0000u); }
static __device__ __forceinline__ float selu(float x) {
    const float scale = 1.0507009873554805f;
    const float alpha = 1.6732632423543772f;
    return x > 0.f ? scale * x : scale * alpha * (expf(x) - 1.f);
}
// 64-lane inclusive scan in-register (no barriers)
static __device__ __forceinline__ u32 wave_iscan(u32 x, int lane) {
    #pragma unroll
    for (int d = 1; d < 64; d <<= 1) {
        u32 y = __shfl_up(x, d, 64);
        if (lane >= d) x += y;
    }
    return x;
}

// ---------------------------------------------------------------------------
// K1 fused (unchanged from round 8 -- its best measured form). Blocks
// [0,784): in-LDS counting sort of 2048 edges by 128-row bucket into an LDS
// tile, flushed with coalesced streaks. Blocks [784,1566): bf16
// h = feat @ kern (register-tiled 4r x 8c, kern in LDS).
// ---------------------------------------------------------------------------
__global__ __launch_bounds__(256) void fused_gemm_sort(
    const float* __restrict__ feat, const float* __restrict__ kern,
    const int* __restrict__ erow, const int* __restrict__ ecol,
    const float* __restrict__ eval, u16* __restrict__ hbf,
    int2* __restrict__ sedge, u32* __restrict__ poff)
{
    __shared__ u32 smem[5665];   // 22.7 KB: gemm uses 16 KB; sort uses all
    const int t = threadIdx.x;

    if (blockIdx.x >= NHB) {
        float* ks = (float*)smem;   // 64x64 kernel, row-major [k][c]
        {
            const float4* k4 = (const float4*)kern;
            float4* ks4 = (float4*)ks;
            #pragma unroll
            for (int i = 0; i < 4; i++) ks4[t + 256 * i] = k4[t + 256 * i];
        }
        __syncthreads();

        const int cgi  = t & 7;                      // 8 col-groups (8 cols)
        const int rg   = t >> 3;                     // 32 row-groups (4 rows)
        const int row0 = (blockIdx.x - NHB) * RPB + rg * 4;

        float4 acc[4][2];
        #pragma unroll
        for (int r = 0; r < 4; r++)
            #pragma unroll
            for (int i = 0; i < 2; i++)
                acc[r][i] = make_float4(0.f, 0.f, 0.f, 0.f);

        #pragma unroll 4
        for (int s = 0; s < 16; s++) {               // k4-step: 4 k-values
            float4 f[4];
            #pragma unroll
            for (int r = 0; r < 4; r++) {
                int row = min(row0 + r, N_NODES - 1);
                f[r] = ((const float4*)(feat + (size_t)row * D))[s];
            }
            float4 kk[4][2];
            #pragma unroll
            for (int kv = 0; kv < 4; kv++)
                #pragma unroll
                for (int i = 0; i < 2; i++)
                    kk[kv][i] = ((const float4*)(ks + (s * 4 + kv) * D))[cgi * 2 + i];
            #pragma unroll
            for (int r = 0; r < 4; r++) {
                #pragma unroll
                for (int kv = 0; kv < 4; kv++) {
                    float fv = (&f[r].x)[kv];
                    #pragma unroll
                    for (int i = 0; i < 2; i++) {
                        acc[r][i].x += fv * kk[kv][i].x;
                        acc[r][i].y += fv * kk[kv][i].y;
                        acc[r][i].z += fv * kk[kv][i].z;
                        acc[r][i].w += fv * kk[kv][i].w;
                    }
                }
            }
        }

        #pragma unroll
        for (int r = 0; r < 4; r++) {
            int row = row0 + r;
            if (row < N_NODES) {
                uint4 o;
                o.x = pack2(acc[r][0].x, acc[r][0].y);
                o.y = pack2(acc[r][0].z, acc[r][0].w);
                o.z = pack2(acc[r][1].x, acc[r][1].y);
                o.w = pack2(acc[r][1].z, acc[r][1].w);
                ((uint4*)(hbf + (size_t)row * D))[cgi] = o;
            }
        }
    } else {
        int2* tile = (int2*)smem;          // 2048 int2 = 16 KB sorted tile
        u32* co    = smem + 4096;          // 783: counts, then offsets in-place
        u32* cu    = co + 783;             // 782 cursors
        u32* part  = cu + 782;             // 4 wave partials   (total 5665 u32)

        for (int i = t; i < 783; i += 256) co[i] = 0u;
        __syncthreads();

        const int hb   = blockIdx.x;
        const int base = hb * EPB;
        const int lane = t & 63;
        const int w    = t >> 6;

        // pass 1: bucket count (native u32 LDS atomics), coalesced erow reads
        #pragma unroll
        for (int k = 0; k < 8; k++) {
            int i = base + k * 256 + t;
            if (i < N_EDGES) atomicAdd(&co[(u32)erow[i] >> 7], 1u);
        }
        __syncthreads();

        // shfl-based exclusive scan over 782 counts, offsets written in-place
        const int i0 = t * 4;
        u32 p = 0u;
        #pragma unroll
        for (int jj = 0; jj < 4; jj++) { int i = i0 + jj; if (i < NBUK) p += co[i]; }
        u32 incl = wave_iscan(p, lane);
        if (lane == 63) part[w] = incl;
        __syncthreads();
        {
            u32 wp = 0u;
            #pragma unroll
            for (int ww = 0; ww < 4; ww++) if (ww < w) wp += part[ww];
            u32 run = incl - p + wp;
            #pragma unroll
            for (int jj = 0; jj < 4; jj++) {
                int i = i0 + jj;
                if (i < NBUK) { u32 cv = co[i]; co[i] = run; cu[i] = run; run += cv; }
            }
            if (t == 0) co[NBUK] = part[0] + part[1] + part[2] + part[3];
        }
        __syncthreads();

        // pass 2: re-read erow (L2-hot), scatter into LDS tile
        #pragma unroll
        for (int k = 0; k < 8; k++) {
            int i = base + k * 256 + t;
            if (i < N_EDGES) {
                u32 r = (u32)erow[i];
                u32 rk = atomicAdd(&cu[r >> 7], 1u);
                tile[rk] = make_int2(ecol[i] | (int)((r & 127u) << 17),
                                     __float_as_int(eval[i]));
            }
        }
        __syncthreads();

        // flush: fully coalesced contiguous int2 stores (slots >= cnt are
        // garbage but never read -- poff runs only cover [0, cnt))
        #pragma unroll
        for (int k = 0; k < 8; k++)
            sedge[(size_t)hb * EPB + k * 256 + t] = tile[k * 256 + t];

        // publish 783 offsets, hb-major: fully coalesced contiguous writes
        for (int i = t; i <= NBUK; i += 256)
            poff[(size_t)hb * POFF_ROW + i] = co[i];
    }
}

// ---------------------------------------------------------------------------
// K2: aggregation. Phase C reverted to round-7's proven 4-wide form (plain
// launch_bounds(1024): R8's copy-rotation collapsed, R9's 8-wide + (1024,8)
// cap SPILLED -- WRITE_SIZE 31->146 MB scratch traffic).
// NEW: eA staging buffer DELETED. Pass 1 reads sedge (runid/combo mapping)
// and only counts rows; pass 2 re-reads the same addresses (L2-hot 16
// KB/block) and scatters DIRECTLY into row-sorted eB. Removes one LDS
// write+read of every edge and 24 KB LDS (60->36 KB).
// ---------------------------------------------------------------------------
__global__ __launch_bounds__(1024) void agg_kernel(
    const u32* __restrict__ poff, const int2* __restrict__ sedge,
    const u16* __restrict__ hbf, const float* __restrict__ skip,
    const float* __restrict__ bias, float* __restrict__ out)
{
    __shared__ int2 eB[CAP];          // 24 KB row-sorted
    __shared__ u32 c[RPB];
    __shared__ u32 o[RPB];
    __shared__ u32 cur[RPB];
    __shared__ u32 combo[NHB];        // rs0[rid] - excl[rid]  (mod 2^32)
    __shared__ u16 runid[CAP];        // edge index -> run id
    __shared__ u32 wsum[16];
    __shared__ u32 wpre[16];
    __shared__ u32 cnt_sh;

    const int t = threadIdx.x;
    const int lane = t & 63;
    const int w = t >> 6;
    const int b = blockIdx.x;

    if (t < RPB) c[t] = 0u;

    // run descriptors: hb-major poff -> scattered 4B loads, L2-hot (97x reuse)
    u32 mylen = 0u, s0 = 0u;
    if (t < NHB) {
        const u32* pr = poff + (size_t)t * POFF_ROW + b;
        s0    = pr[0];
        mylen = pr[1] - s0;
    }
    // shfl scan of 784 run lengths: wave scans + 16 wave partials
    u32 incl = wave_iscan(mylen, lane);
    if (lane == 63) wsum[w] = incl;
    __syncthreads();
    if (w == 0) {
        u32 v = (lane < 16) ? wsum[lane] : 0u;
        u32 pp = wave_iscan(v, lane);
        if (lane < 16) wpre[lane] = pp - v;       // exclusive wave prefix
        if (lane == 15) cnt_sh = min(pp, (u32)CAP);
    }
    __syncthreads();
    incl += wpre[w];
    const u32 excl = incl - mylen;
    if (t < NHB) {
        combo[t] = s0 - excl;                      // wrapping arithmetic
        for (u32 j = excl; j < incl; j++)
            if (j < (u32)CAP) runid[j] = (u16)t;
    }
    __syncthreads();

    const u32 cnt = cnt_sh;

    // pass 1: edge-parallel row COUNT straight from global (O(1) run lookup)
    for (u32 j = (u32)t; j < cnt; j += 1024u) {
        u32 rid = (u32)runid[j];
        u32 src = rid * (u32)EPB + combo[rid] + j; // == rid*EPB + rs0 + (j-excl)
        int2 e = sedge[(size_t)src];
        atomicAdd(&c[(u32)e.x >> 17], 1u);
    }
    __syncthreads();

    // shfl-based exclusive scan over 128 row counts (2 barriers)
    {
        u32 x = (t < RPB) ? c[t] : 0u;
        u32 ri = wave_iscan(x, lane);
        if (lane == 63) wsum[w] = ri;
        __syncthreads();
        if (t < RPB) {
            u32 add = (w == 1) ? wsum[0] : 0u;
            u32 e = ri + add - x;
            o[t] = e; cur[t] = e;
        }
        __syncthreads();
    }

    // pass 2: re-read sedge (L2-hot) and scatter DIRECTLY into eB
    for (u32 j = (u32)t; j < cnt; j += 1024u) {
        u32 rid = (u32)runid[j];
        u32 src = rid * (u32)EPB + combo[rid] + j;
        int2 e = sedge[(size_t)src];
        u32 rl = (u32)e.x >> 17;
        u32 rk = atomicAdd(&cur[rl], 1u);
        eB[rk] = make_int2(e.x & 0x1FFFF, e.y);
    }
    __syncthreads();

    // phase C: one row per 8-lane group, 8 dims/lane, x4 unroll (round-7 form)
    const int rows = min(RPB, N_NODES - b * RPB);
    const int g  = t >> 3;            // 0..127: local row
    const int dg = t & 7;             // dim group (8 dims = one uint4)

    float a0 = 0.f, a1 = 0.f, a2 = 0.f, a3 = 0.f;
    float a4 = 0.f, a5 = 0.f, a6 = 0.f, a7 = 0.f;

    u32 jb = 0u, jend = 0u;
    if (g < rows) {
        jb = o[g];
        jend = min(jb + c[g], (u32)CAP);
    }

    u32 j = jb;
    for (; j + 3u < jend; j += 4u) {
        int2 e0 = eB[j];                  // 8-lane broadcast (conflict-free)
        int2 e1 = eB[j + 1u];
        int2 e2 = eB[j + 2u];
        int2 e3 = eB[j + 3u];
        float v0 = __int_as_float(e0.y);
        float v1 = __int_as_float(e1.y);
        float v2 = __int_as_float(e2.y);
        float v3 = __int_as_float(e3.y);
        uint4 h0 = ((const uint4*)(hbf + (size_t)e0.x * D))[dg];
        uint4 h1 = ((const uint4*)(hbf + (size_t)e1.x * D))[dg];
        uint4 h2 = ((const uint4*)(hbf + (size_t)e2.x * D))[dg];
        uint4 h3 = ((const uint4*)(hbf + (size_t)e3.x * D))[dg];
        a0 += v0 * bflo(h0.x); a1 += v0 * bfhi(h0.x);
        a2 += v0 * bflo(h0.y); a3 += v0 * bfhi(h0.y);
        a4 += v0 * bflo(h0.z); a5 += v0 * bfhi(h0.z);
        a6 += v0 * bflo(h0.w); a7 += v0 * bfhi(h0.w);
        a0 += v1 * bflo(h1.x); a1 += v1 * bfhi(h1.x);
        a2 += v1 * bflo(h1.y); a3 += v1 * bfhi(h1.y);
        a4 += v1 * bflo(h1.z); a5 += v1 * bfhi(h1.z);
        a6 += v1 * bflo(h1.w); a7 += v1 * bfhi(h1.w);
        a0 += v2 * bflo(h2.x); a1 += v2 * bfhi(h2.x);
        a2 += v2 * bflo(h2.y); a3 += v2 * bfhi(h2.y);
        a4 += v2 * bflo(h2.z); a5 += v2 * bfhi(h2.z);
        a6 += v2 * bflo(h2.w); a7 += v2 * bfhi(h2.w);
        a0 += v3 * bflo(h3.x); a1 += v3 * bfhi(h3.x);
        a2 += v3 * bflo(h3.y); a3 += v3 * bfhi(h3.y);
        a4 += v3 * bflo(h3.z); a5 += v3 * bfhi(h3.z);
        a6 += v3 * bflo(h3.w); a7 += v3 * bfhi(h3.w);
    }
    for (; j < jend; j++) {
        int2 e0 = eB[j];
        float v0 = __int_as_float(e0.y);
        uint4 h0 = ((const uint4*)(hbf + (size_t)e0.x * D))[dg];
        a0 += v0 * bflo(h0.x); a1 += v0 * bfhi(h0.x);
        a2 += v0 * bflo(h0.y); a3 += v0 * bfhi(h0.y);
        a4 += v0 * bflo(h0.z); a5 += v0 * bfhi(h0.z);
        a6 += v0 * bflo(h0.w); a7 += v0 * bfhi(h0.w);
    }

    // epilogue: all lanes active (8 lanes x 8 dims per row), coalesced
    if (g < rows) {
        const int grow = b * RPB + g;
        uint4 hr = ((const uint4*)(hbf + (size_t)grow * D))[dg];
        float4 s0v = ((const float4*)skip)[2 * dg];
        float4 s1v = ((const float4*)skip)[2 * dg + 1];
        float4 b0v = ((const float4*)bias)[2 * dg];
        float4 b1v = ((const float4*)bias)[2 * dg + 1];
        float4 x0, x1;
        x0.x = selu(bflo(hr.x) * s0v.x + b0v.x + a0);
        x0.y = selu(bfhi(hr.x) * s0v.y + b0v.y + a1);
        x0.z = selu(bflo(hr.y) * s0v.z + b0v.z + a2);
        x0.w = selu(bfhi(hr.y) * s0v.w + b0v.w + a3);
        x1.x = selu(bflo(hr.z) * s1v.x + b1v.x + a4);
        x1.y = selu(bfhi(hr.z) * s1v.y + b1v.y + a5);
        x1.z = selu(bflo(hr.w) * s1v.z + b1v.z + a6);
        x1.w = selu(bfhi(hr.w) * s1v.w + b1v.w + a7);
        ((float4*)(out + (size_t)grow * D))[2 * dg]     = x0;
        ((float4*)(out + (size_t)grow * D))[2 * dg + 1] = x1;
    }
}

extern "C" void kernel_launch(void* const* d_in, const int* in_sizes, int n_in,
                              void* d_out, int out_size, void* d_ws, size_t ws_size,
                              hipStream_t stream)
{
    const float* feat = (const float*)d_in[0];
    const float* kern = (const float*)d_in[1];
    const float* bias = (const float*)d_in[2];
    const float* skip = (const float*)d_in[3];
    const int*   erow = (const int*)d_in[4];
    const int*   ecol = (const int*)d_in[5];
    const float* eval = (const float*)d_in[6];
    float* out = (float*)d_out;

    // workspace layout (all segments 16B-aligned)
    u16*  hbf   = (u16*)d_ws;                             // 6,400,000 u16 (12.8 MB)
    u32*  poff  = (u32*)(hbf + (size_t)N_NODES * D);      // 784*784 u32 (2.46 MB)
    int2* sedge = (int2*)(poff + (size_t)NHB * POFF_ROW); // 784*2048 int2 (12.85 MB)
    // total ~28.1 MB

    hipLaunchKernelGGL(fused_gemm_sort, dim3(NGB + NHB), dim3(256), 0, stream,
                       feat, kern, erow, ecol, eval, hbf, sedge, poff);
    hipLaunchKernelGGL(agg_kernel, dim3(NBUK), dim3(1024), 0, stream,
                       poff, sedge, hbf, skip, bias, out);
}

// Round 11
// 161.271 us; speedup vs baseline: 1.3152x; 1.0551x over previous
//
#include <hip/hip_runtime.h>
#include <math.h>

#define N_NODES 100000
#define N_EDGES 1600000
#define D 64
#define RPB 128                  // rows per bucket
#define NBUK 782                 // ceil(N_NODES/128)
#define CAP 3072                 // LDS edge buffer (bucket mean 2048, +22 sigma)
#define NGB 782                  // gemm blocks (128 rows each)
#define NHB 784                  // sort blocks (FIRST in grid: poles start at t=0)
#define EPB 2048                 // edges per sort block (784*2048 >= 1.6M)
#define POFF_ROW 784             // u32 stride of poff[hb][*] (hb-major)

typedef unsigned int u32;
typedef unsigned short u16;

static __device__ __forceinline__ u32 f2bf(float x) {   // RNE fp32->bf16 (low 16)
    u32 u = __float_as_uint(x);
    u32 r = u + 0x7FFFu + ((u >> 16) & 1u);
    return r >> 16;
}
static __device__ __forceinline__ u32 pack2(float a, float b) {
    return f2bf(a) | (f2bf(b) << 16);
}
static __device__ __forceinline__ float bflo(u32 u) { return __uint_as_float(u << 16); }
static __device__ __forceinline__ float bfhi(u32 u) { return __uint_as_float(u & 0xFFFF0000u); }
static __device__ __forceinline__ float selu(float x) {
    const float scale = 1.0507009873554805f;
    const float alpha = 1.6732632423543772f;
    return x > 0.f ? scale * x : scale * alpha * (expf(x) - 1.f);
}
// 64-lane inclusive scan in-register (no barriers)
static __device__ __forceinline__ u32 wave_iscan(u32 x, int lane) {
    #pragma unroll
    for (int d = 1; d < 64; d <<= 1) {
        u32 y = __shfl_up(x, d, 64);
        if (lane >= d) x += y;
    }
    return x;
}

// ---------------------------------------------------------------------------
// K1 fused (round-8 form, best measured ~46 us). Blocks [0,784): in-LDS
// counting sort of 2048 edges by 128-row bucket into an LDS tile, flushed
// with coalesced streaks (random 8-B global scatter was write-amplifying
// WRITE_SIZE ~68 MB). Blocks [784,1566): bf16 h = feat @ kern
// (register-tiled 4r x 8c, kern in LDS). Sort blocks lead the grid so their
// long poles overlap the gemm stream; 22.7 KB LDS keeps all blocks
// co-resident.
// ---------------------------------------------------------------------------
__global__ __launch_bounds__(256) void fused_gemm_sort(
    const float* __restrict__ feat, const float* __restrict__ kern,
    const int* __restrict__ erow, const int* __restrict__ ecol,
    const float* __restrict__ eval, u16* __restrict__ hbf,
    int2* __restrict__ sedge, u32* __restrict__ poff)
{
    __shared__ u32 smem[5665];   // 22.7 KB: gemm uses 16 KB; sort uses all
    const int t = threadIdx.x;

    if (blockIdx.x >= NHB) {
        float* ks = (float*)smem;   // 64x64 kernel, row-major [k][c]
        {
            const float4* k4 = (const float4*)kern;
            float4* ks4 = (float4*)ks;
            #pragma unroll
            for (int i = 0; i < 4; i++) ks4[t + 256 * i] = k4[t + 256 * i];
        }
        __syncthreads();

        const int cgi  = t & 7;                      // 8 col-groups (8 cols)
        const int rg   = t >> 3;                     // 32 row-groups (4 rows)
        const int row0 = (blockIdx.x - NHB) * RPB + rg * 4;

        float4 acc[4][2];
        #pragma unroll
        for (int r = 0; r < 4; r++)
            #pragma unroll
            for (int i = 0; i < 2; i++)
                acc[r][i] = make_float4(0.f, 0.f, 0.f, 0.f);

        #pragma unroll 4
        for (int s = 0; s < 16; s++) {               // k4-step: 4 k-values
            float4 f[4];
            #pragma unroll
            for (int r = 0; r < 4; r++) {
                int row = min(row0 + r, N_NODES - 1);
                f[r] = ((const float4*)(feat + (size_t)row * D))[s];
            }
            float4 kk[4][2];
            #pragma unroll
            for (int kv = 0; kv < 4; kv++)
                #pragma unroll
                for (int i = 0; i < 2; i++)
                    kk[kv][i] = ((const float4*)(ks + (s * 4 + kv) * D))[cgi * 2 + i];
            #pragma unroll
            for (int r = 0; r < 4; r++) {
                #pragma unroll
                for (int kv = 0; kv < 4; kv++) {
                    float fv = (&f[r].x)[kv];
                    #pragma unroll
                    for (int i = 0; i < 2; i++) {
                        acc[r][i].x += fv * kk[kv][i].x;
                        acc[r][i].y += fv * kk[kv][i].y;
                        acc[r][i].z += fv * kk[kv][i].z;
                        acc[r][i].w += fv * kk[kv][i].w;
                    }
                }
            }
        }

        #pragma unroll
        for (int r = 0; r < 4; r++) {
            int row = row0 + r;
            if (row < N_NODES) {
                uint4 o;
                o.x = pack2(acc[r][0].x, acc[r][0].y);
                o.y = pack2(acc[r][0].z, acc[r][0].w);
                o.z = pack2(acc[r][1].x, acc[r][1].y);
                o.w = pack2(acc[r][1].z, acc[r][1].w);
                ((uint4*)(hbf + (size_t)row * D))[cgi] = o;
            }
        }
    } else {
        int2* tile = (int2*)smem;          // 2048 int2 = 16 KB sorted tile
        u32* co    = smem + 4096;          // 783: counts, then offsets in-place
        u32* cu    = co + 783;             // 782 cursors
        u32* part  = cu + 782;             // 4 wave partials   (total 5665 u32)

        for (int i = t; i < 783; i += 256) co[i] = 0u;
        __syncthreads();

        const int hb   = blockIdx.x;
        const int base = hb * EPB;
        const int lane = t & 63;
        const int w    = t >> 6;

        // pass 1: bucket count (native u32 LDS atomics), coalesced erow reads
        #pragma unroll
        for (int k = 0; k < 8; k++) {
            int i = base + k * 256 + t;
            if (i < N_EDGES) atomicAdd(&co[(u32)erow[i] >> 7], 1u);
        }
        __syncthreads();

        // shfl-based exclusive scan over 782 counts, offsets written in-place
        const int i0 = t * 4;
        u32 p = 0u;
        #pragma unroll
        for (int jj = 0; jj < 4; jj++) { int i = i0 + jj; if (i < NBUK) p += co[i]; }
        u32 incl = wave_iscan(p, lane);
        if (lane == 63) part[w] = incl;
        __syncthreads();
        {
            u32 wp = 0u;
            #pragma unroll
            for (int ww = 0; ww < 4; ww++) if (ww < w) wp += part[ww];
            u32 run = incl - p + wp;
            #pragma unroll
            for (int jj = 0; jj < 4; jj++) {
                int i = i0 + jj;
                if (i < NBUK) { u32 cv = co[i]; co[i] = run; cu[i] = run; run += cv; }
            }
            if (t == 0) co[NBUK] = part[0] + part[1] + part[2] + part[3];
        }
        __syncthreads();

        // pass 2: re-read erow (L2-hot), scatter into LDS tile
        #pragma unroll
        for (int k = 0; k < 8; k++) {
            int i = base + k * 256 + t;
            if (i < N_EDGES) {
                u32 r = (u32)erow[i];
                u32 rk = atomicAdd(&cu[r >> 7], 1u);
                tile[rk] = make_int2(ecol[i] | (int)((r & 127u) << 17),
                                     __float_as_int(eval[i]));
            }
        }
        __syncthreads();

        // flush: fully coalesced contiguous int2 stores (slots >= cnt are
        // garbage but never read -- poff runs only cover [0, cnt))
        #pragma unroll
        for (int k = 0; k < 8; k++)
            sedge[(size_t)hb * EPB + k * 256 + t] = tile[k * 256 + t];

        // publish 783 offsets, hb-major: fully coalesced contiguous writes
        for (int i = t; i <= NBUK; i += 256)
            poff[(size_t)hb * POFF_ROW + i] = co[i];
    }
}

// ---------------------------------------------------------------------------
// K2: aggregation (round-7 form, best measured 50.4 us).
//  1) descriptor gather from hb-major poff; shfl-scan of 784 run lengths;
//     runid[j]/combo[rid] map -> O(1) run lookup (no binary-search chain).
//  2) Stage: edge-parallel; single global edge load into eA, count row.
//     (eA is essential: R10 showed the "re-read instead" variant misses L2
//     -- +28 MB FETCH, +7 us -- because the hbf gather stream evicts the
//     staging lines between passes.)
//  3) shfl-based 128-row scan; LDS->LDS scatter into row-sorted eB.
//  4) Phase C: one row per 8-lane group, 8 dims/lane, x4 unroll, no
//     cross-lane reduce; coalesced all-lane epilogue. (4-wide is the proven
//     form: R8 copy-rotation collapsed to VGPR 32, R9 8-wide + (1024,8)
//     spilled to scratch -- WRITE 31->146 MB.)
// ---------------------------------------------------------------------------
__global__ __launch_bounds__(1024) void agg_kernel(
    const u32* __restrict__ poff, const int2* __restrict__ sedge,
    const u16* __restrict__ hbf, const float* __restrict__ skip,
    const float* __restrict__ bias, float* __restrict__ out)
{
    __shared__ int2 eA[CAP];          // 24 KB staged (bucket-contiguous)
    __shared__ int2 eB[CAP];          // 24 KB row-sorted
    __shared__ u32 c[RPB];
    __shared__ u32 o[RPB];
    __shared__ u32 cur[RPB];
    __shared__ u32 combo[NHB];        // rs0[rid] - excl[rid]  (mod 2^32)
    __shared__ u16 runid[CAP];        // edge index -> run id
    __shared__ u32 wsum[16];
    __shared__ u32 wpre[16];
    __shared__ u32 cnt_sh;

    const int t = threadIdx.x;
    const int lane = t & 63;
    const int w = t >> 6;
    const int b = blockIdx.x;

    if (t < RPB) c[t] = 0u;

    // run descriptors: hb-major poff -> scattered 4B loads, L2-hot (97x reuse)
    u32 mylen = 0u, s0 = 0u;
    if (t < NHB) {
        const u32* pr = poff + (size_t)t * POFF_ROW + b;
        s0    = pr[0];
        mylen = pr[1] - s0;
    }
    // shfl scan of 784 run lengths: wave scans + 16 wave partials
    u32 incl = wave_iscan(mylen, lane);
    if (lane == 63) wsum[w] = incl;
    __syncthreads();
    if (w == 0) {
        u32 v = (lane < 16) ? wsum[lane] : 0u;
        u32 pp = wave_iscan(v, lane);
        if (lane < 16) wpre[lane] = pp - v;       // exclusive wave prefix
        if (lane == 15) cnt_sh = min(pp, (u32)CAP);
    }
    __syncthreads();
    incl += wpre[w];
    const u32 excl = incl - mylen;
    if (t < NHB) {
        combo[t] = s0 - excl;                      // wrapping arithmetic
        for (u32 j = excl; j < incl; j++)
            if (j < (u32)CAP) runid[j] = (u16)t;
    }
    __syncthreads();

    const u32 cnt = cnt_sh;

    // stage: edge-parallel, O(1) run lookup, single global read, row count
    for (u32 j = (u32)t; j < cnt; j += 1024u) {
        u32 rid = (u32)runid[j];
        u32 src = rid * (u32)EPB + combo[rid] + j; // == rid*EPB + rs0 + (j-excl)
        int2 e = sedge[(size_t)src];
        eA[j] = e;
        atomicAdd(&c[(u32)e.x >> 17], 1u);
    }
    __syncthreads();

    // shfl-based exclusive scan over 128 row counts (2 barriers)
    {
        u32 x = (t < RPB) ? c[t] : 0u;
        u32 ri = wave_iscan(x, lane);
        if (lane == 63) wsum[w] = ri;
        __syncthreads();
        if (t < RPB) {
            u32 add = (w == 1) ? wsum[0] : 0u;
            u32 e = ri + add - x;
            o[t] = e; cur[t] = e;
        }
        __syncthreads();
    }

    // scatter LDS->LDS into row-sorted eB (rk < cnt <= CAP by construction)
    for (u32 j = (u32)t; j < cnt; j += 1024u) {
        int2 e = eA[j];
        u32 rl = (u32)e.x >> 17;
        u32 rk = atomicAdd(&cur[rl], 1u);
        eB[rk] = make_int2(e.x & 0x1FFFF, e.y);
    }
    __syncthreads();

    // phase C: one row per 8-lane group, 8 dims/lane, x4 unroll
    const int rows = min(RPB, N_NODES - b * RPB);
    const int g  = t >> 3;            // 0..127: local row
    const int dg = t & 7;             // dim group (8 dims = one uint4)

    float a0 = 0.f, a1 = 0.f, a2 = 0.f, a3 = 0.f;
    float a4 = 0.f, a5 = 0.f, a6 = 0.f, a7 = 0.f;

    u32 jb = 0u, jend = 0u;
    if (g < rows) {
        jb = o[g];
        jend = min(jb + c[g], (u32)CAP);
    }

    u32 j = jb;
    for (; j + 3u < jend; j += 4u) {
        int2 e0 = eB[j];                  // 8-lane broadcast (conflict-free)
        int2 e1 = eB[j + 1u];
        int2 e2 = eB[j + 2u];
        int2 e3 = eB[j + 3u];
        float v0 = __int_as_float(e0.y);
        float v1 = __int_as_float(e1.y);
        float v2 = __int_as_float(e2.y);
        float v3 = __int_as_float(e3.y);
        uint4 h0 = ((const uint4*)(hbf + (size_t)e0.x * D))[dg];
        uint4 h1 = ((const uint4*)(hbf + (size_t)e1.x * D))[dg];
        uint4 h2 = ((const uint4*)(hbf + (size_t)e2.x * D))[dg];
        uint4 h3 = ((const uint4*)(hbf + (size_t)e3.x * D))[dg];
        a0 += v0 * bflo(h0.x); a1 += v0 * bfhi(h0.x);
        a2 += v0 * bflo(h0.y); a3 += v0 * bfhi(h0.y);
        a4 += v0 * bflo(h0.z); a5 += v0 * bfhi(h0.z);
        a6 += v0 * bflo(h0.w); a7 += v0 * bfhi(h0.w);
        a0 += v1 * bflo(h1.x); a1 += v1 * bfhi(h1.x);
        a2 += v1 * bflo(h1.y); a3 += v1 * bfhi(h1.y);
        a4 += v1 * bflo(h1.z); a5 += v1 * bfhi(h1.z);
        a6 += v1 * bflo(h1.w); a7 += v1 * bfhi(h1.w);
        a0 += v2 * bflo(h2.x); a1 += v2 * bfhi(h2.x);
        a2 += v2 * bflo(h2.y); a3 += v2 * bfhi(h2.y);
        a4 += v2 * bflo(h2.z); a5 += v2 * bfhi(h2.z);
        a6 += v2 * bflo(h2.w); a7 += v2 * bfhi(h2.w);
        a0 += v3 * bflo(h3.x); a1 += v3 * bfhi(h3.x);
        a2 += v3 * bflo(h3.y); a3 += v3 * bfhi(h3.y);
        a4 += v3 * bflo(h3.z); a5 += v3 * bfhi(h3.z);
        a6 += v3 * bflo(h3.w); a7 += v3 * bfhi(h3.w);
    }
    for (; j < jend; j++) {
        int2 e0 = eB[j];
        float v0 = __int_as_float(e0.y);
        uint4 h0 = ((const uint4*)(hbf + (size_t)e0.x * D))[dg];
        a0 += v0 * bflo(h0.x); a1 += v0 * bfhi(h0.x);
        a2 += v0 * bflo(h0.y); a3 += v0 * bfhi(h0.y);
        a4 += v0 * bflo(h0.z); a5 += v0 * bfhi(h0.z);
        a6 += v0 * bflo(h0.w); a7 += v0 * bfhi(h0.w);
    }

    // epilogue: all lanes active (8 lanes x 8 dims per row), coalesced
    if (g < rows) {
        const int grow = b * RPB + g;
        uint4 hr = ((const uint4*)(hbf + (size_t)grow * D))[dg];
        float4 s0v = ((const float4*)skip)[2 * dg];
        float4 s1v = ((const float4*)skip)[2 * dg + 1];
        float4 b0v = ((const float4*)bias)[2 * dg];
        float4 b1v = ((const float4*)bias)[2 * dg + 1];
        float4 x0, x1;
        x0.x = selu(bflo(hr.x) * s0v.x + b0v.x + a0);
        x0.y = selu(bfhi(hr.x) * s0v.y + b0v.y + a1);
        x0.z = selu(bflo(hr.y) * s0v.z + b0v.z + a2);
        x0.w = selu(bfhi(hr.y) * s0v.w + b0v.w + a3);
        x1.x = selu(bflo(hr.z) * s1v.x + b1v.x + a4);
        x1.y = selu(bfhi(hr.z) * s1v.y + b1v.y + a5);
        x1.z = selu(bflo(hr.w) * s1v.z + b1v.z + a6);
        x1.w = selu(bfhi(hr.w) * s1v.w + b1v.w + a7);
        ((float4*)(out + (size_t)grow * D))[2 * dg]     = x0;
        ((float4*)(out + (size_t)grow * D))[2 * dg + 1] = x1;
    }
}

extern "C" void kernel_launch(void* const* d_in, const int* in_sizes, int n_in,
                              void* d_out, int out_size, void* d_ws, size_t ws_size,
                              hipStream_t stream)
{
    const float* feat = (const float*)d_in[0];
    const float* kern = (const float*)d_in[1];
    const float* bias = (const float*)d_in[2];
    const float* skip = (const float*)d_in[3];
    const int*   erow = (const int*)d_in[4];
    const int*   ecol = (const int*)d_in[5];
    const float* eval = (const float*)d_in[6];
    float* out = (float*)d_out;

    // workspace layout (all segments 16B-aligned)
    u16*  hbf   = (u16*)d_ws;                             // 6,400,000 u16 (12.8 MB)
    u32*  poff  = (u32*)(hbf + (size_t)N_NODES * D);      // 784*784 u32 (2.46 MB)
    int2* sedge = (int2*)(poff + (size_t)NHB * POFF_ROW); // 784*2048 int2 (12.85 MB)
    // total ~28.1 MB

    hipLaunchKernelGGL(fused_gemm_sort, dim3(NGB + NHB), dim3(256), 0, stream,
                       feat, kern, erow, ecol, eval, hbf, sedge, poff);
    hipLaunchKernelGGL(agg_kernel, dim3(NBUK), dim3(1024), 0, stream,
                       poff, sedge, hbf, skip, bias, out);
}